// Round 1
// baseline (317.452 us; speedup 1.0000x reference)
//
#include <hip/hip_runtime.h>
#include <stdint.h>

typedef unsigned short u16;
typedef unsigned long long u64;
using f32x4 = __attribute__((ext_vector_type(4))) float;
using s16x8 = __attribute__((ext_vector_type(8))) short;
using u16x4 = __attribute__((ext_vector_type(4))) unsigned short;

static constexpr float kScale = 0.08838834764831845f;  // 128^-0.5

__device__ __forceinline__ u16 f2bf(float f) {
  uint32_t u = __float_as_uint(f);
  u += 0x7fffu + ((u >> 16) & 1u);   // RNE
  return (u16)(u >> 16);
}

// MFMA via inline asm (D=C tied). 16x16x32 bf16: a/b = 8 bf16/lane (row|col = lane&15,
// k = 8*(lane>>4)+j); C/D: col = lane&15, row = 4*(lane>>4)+reg  [guide §3, m89/m91].
__device__ __forceinline__ void mfma16(f32x4& d, s16x8 a, s16x8 b) {
  asm volatile("v_mfma_f32_16x16x32_bf16 %0, %1, %2, %0" : "+v"(d) : "v"(a), "v"(b));
}
__device__ __forceinline__ f32x4 mfma16_z(s16x8 a, s16x8 b) {
  f32x4 d;
  asm volatile("v_mfma_f32_16x16x32_bf16 %0, %1, %2, 0" : "=&v"(d) : "v"(a), "v"(b));
  return d;
}

// async global->LDS, 16B per lane; LDS dest = wave-uniform base + lane*16 (m104).
__device__ __forceinline__ void g2lds16(const void* g, void* l) {
  __builtin_amdgcn_global_load_lds(
      (__attribute__((address_space(1))) void*)(uintptr_t)g,
      (__attribute__((address_space(3))) void*)(uint32_t)(uintptr_t)l, 16, 0, 0);
}

// ---------------- elementwise converts ----------------
__global__ __launch_bounds__(256) void cvt_f32_bf16(const float* __restrict__ in,
                                                    u16* __restrict__ out, int n) {
  int i = (blockIdx.x * 256 + threadIdx.x) * 4;
  if (i + 3 < n) {
    f32x4 v = *(const f32x4*)(in + i);
    u16x4 o = {f2bf(v.x), f2bf(v.y), f2bf(v.z), f2bf(v.w)};
    *(u16x4*)(out + i) = o;
  }
}

// 4x (1024x1024) weight converts into one contiguous buffer
__global__ __launch_bounds__(256) void cvt4(const float* __restrict__ a, const float* __restrict__ b,
                                            const float* __restrict__ c, const float* __restrict__ d,
                                            u16* __restrict__ out) {
  int z = blockIdx.y;
  const float* in = z == 0 ? a : z == 1 ? b : z == 2 ? c : d;
  int i = (blockIdx.x * 256 + threadIdx.x) * 4;
  f32x4 v = *(const f32x4*)(in + i);
  u16x4 o = {f2bf(v.x), f2bf(v.y), f2bf(v.z), f2bf(v.w)};
  *(u16x4*)(out + (size_t)z * 1048576 + i) = o;
}

// qkv_w (R=3072 x C=1024 f32) -> qkv_wT (C x R bf16)
__global__ __launch_bounds__(256) void transpose_f32_bf16(const float* __restrict__ in,
                                                          u16* __restrict__ out, int R, int C) {
  __shared__ u16 tile[32][33];
  int bx = blockIdx.x, by = blockIdx.y;
  int tx = threadIdx.x & 31, ty = threadIdx.x >> 5;
#pragma unroll
  for (int k = 0; k < 4; ++k)
    tile[ty + k * 8][tx] = f2bf(in[(size_t)(by * 32 + ty + k * 8) * C + bx * 32 + tx]);
  __syncthreads();
#pragma unroll
  for (int k = 0; k < 4; ++k)
    out[(size_t)(bx * 32 + ty + k * 8) * R + by * 32 + tx] = tile[tx][ty + k * 8];
}

// combined bias: cb[z][o] = sum_m W_z[o][m]*qkv_b[z*1024+m] + b_z[o]   (fp32 exact)
__global__ __launch_bounds__(256) void cbias3(const float* __restrict__ qw, const float* __restrict__ kw,
                                              const float* __restrict__ vw, const float* __restrict__ qkvb,
                                              const float* __restrict__ qb, const float* __restrict__ kb,
                                              const float* __restrict__ vb, float* __restrict__ out) {
  int z = blockIdx.y;
  const float* w = z == 0 ? qw : (z == 1 ? kw : vw);
  const float* ba = z == 0 ? qb : (z == 1 ? kb : vb);
  const float* bi = qkvb + z * 1024;
  int o = blockIdx.x * 4 + (threadIdx.x >> 6);
  int lane = threadIdx.x & 63;
  float s = 0.f;
  for (int m = lane; m < 1024; m += 64) s += w[o * 1024 + m] * bi[m];
#pragma unroll
  for (int d = 1; d < 64; d <<= 1) s += __shfl_xor(s, d);
  if (lane == 0) out[z * 1024 + o] = s + ba[o];
}

// attn_mask (2048x2048 int32) -> bit-packed rows (2048 x 32 u64), bit j = mask[row][w*64+j]==1
__global__ __launch_bounds__(256) void pack_mask(const int* __restrict__ m, u64* __restrict__ pm) {
  int row = blockIdx.x;
  int wv = threadIdx.x >> 6, lane = threadIdx.x & 63;
#pragma unroll
  for (int i = 0; i < 8; ++i) {
    int word = wv * 8 + i;
    u64 b = __ballot(m[(size_t)row * 2048 + word * 64 + lane] == 1);
    if (lane == 0) pm[(size_t)row * 32 + word] = b;
  }
}

// ---------------- NT GEMM: C[M,N] = A[M,K] * B[N,K]^T (+bias), m97-style 128^2 tile ----------
// z-batched via blockIdx.z with element strides. OUT_T in {u16(bf16), float}.
template <typename OUT_T, bool BIAS_PER_ROW>
__global__ __launch_bounds__(256, 2) void gemm_nt(const u16* __restrict__ A, int lda, long bsA,
                                                  const u16* __restrict__ B, int ldb, long bsB,
                                                  OUT_T* __restrict__ C, int ldc, long bsC,
                                                  const float* __restrict__ bias, long bsBias,
                                                  int NtilesN, int K) {
  __shared__ __align__(16) u16 As[128 * 64];
  __shared__ __align__(16) u16 Bs[128 * 64];
  const int z = blockIdx.z;
  A += (size_t)z * bsA; B += (size_t)z * bsB; C += (size_t)z * bsC;
  if (bias) bias += (size_t)z * bsBias;
  const int tm = blockIdx.x / NtilesN, tn = blockIdx.x % NtilesN;
  const int tid = threadIdx.x, lane = tid & 63, w = tid >> 6;
  const int wm = w >> 1, wn = w & 1;
  const int q = lane & 15, g = lane >> 4;
  f32x4 acc[4][4] = {};

  const u16* Ab = A + (size_t)(tm * 128 + (tid >> 3)) * lda + ((tid & 7) << 3);
  const u16* Bb = B + (size_t)(tn * 128 + (tid >> 3)) * ldb + ((tid & 7) << 3);
  char* AsW = (char*)As + (w << 10);
  char* BsW = (char*)Bs + (w << 10);

  for (int k0 = 0; k0 < K; k0 += 64) {
#pragma unroll
    for (int it = 0; it < 4; ++it) {
      g2lds16(Ab + (size_t)(it * 32) * lda + k0, AsW + it * 4096);
      g2lds16(Bb + (size_t)(it * 32) * ldb + k0, BsW + it * 4096);
    }
    __syncthreads();
#pragma unroll
    for (int kk = 0; kk < 2; ++kk) {
      s16x8 af[4], bf[4];
#pragma unroll
      for (int i = 0; i < 4; ++i)
        af[i] = *(const s16x8*)((const char*)As + (wm * 64 + i * 16 + q) * 128 + kk * 64 + g * 16);
#pragma unroll
      for (int i = 0; i < 4; ++i)
        bf[i] = *(const s16x8*)((const char*)Bs + (wn * 64 + i * 16 + q) * 128 + kk * 64 + g * 16);
#pragma unroll
      for (int mf = 0; mf < 4; ++mf)
#pragma unroll
        for (int nf = 0; nf < 4; ++nf) mfma16(acc[mf][nf], af[mf], bf[nf]);
    }
    __syncthreads();
  }
  asm volatile("s_nop 7\n\ts_nop 7");  // MFMA->VALU hazard (inline asm invisible to recognizer)
#pragma unroll
  for (int mf = 0; mf < 4; ++mf)
#pragma unroll
    for (int nf = 0; nf < 4; ++nf) {
      const int row = tm * 128 + wm * 64 + mf * 16 + g * 4;
      const int col = tn * 128 + wn * 64 + nf * 16 + q;
      float bc = (!BIAS_PER_ROW && bias) ? bias[col] : 0.f;
#pragma unroll
      for (int r = 0; r < 4; ++r) {
        float v = acc[mf][nf][r];
        if (bias) v += BIAS_PER_ROW ? bias[row + r] : bc;
        if constexpr (sizeof(OUT_T) == 2)
          C[(size_t)(row + r) * ldc + col] = (OUT_T)f2bf(v);
        else
          C[(size_t)(row + r) * ldc + col] = (OUT_T)v;
      }
    }
}

// ---------------- flash attention ----------------
// Q,K: (8192 x 1024) bf16 row=token, head h at cols [h*128,h*128+128).
// Vt:  (1024 x 8192) bf16, row = h*128+d, col = b*2048+s.
// Grid (16 qtiles, 8 heads, 4 batch); 4 waves x 32 q-rows, KV tile 64.
__global__ __launch_bounds__(256, 2) void attn_fwd(const u16* __restrict__ Qb, const u16* __restrict__ Kb,
                                                   const u16* __restrict__ Vt, const u64* __restrict__ pmask,
                                                   u16* __restrict__ Ob) {
  __shared__ __align__(16) char K_lds[16384];  // [64 kv][128 d], 16B-chunk XOR (kv&7) swizzle
  __shared__ __align__(16) char V_lds[16384];  // [128 d][64 kv], chunk XOR (d&7)
  __shared__ __align__(16) char P_lds[16384];  // [128 q][64 kv], chunk XOR (q&7)
  const int qt = blockIdx.x, h = blockIdx.y, b = blockIdx.z;
  const int tid = threadIdx.x, w = tid >> 6, lane = tid & 63;
  const int q = lane & 15, g = lane >> 4;
  const int q0 = qt * 128;

  s16x8 qf[2][4];
#pragma unroll
  for (int m = 0; m < 2; ++m)
#pragma unroll
    for (int kk = 0; kk < 4; ++kk)
      qf[m][kk] = *(const s16x8*)(Qb + (size_t)(b * 2048 + q0 + w * 32 + m * 16 + q) * 1024 +
                                  h * 128 + kk * 32 + g * 8);

  f32x4 oacc[2][8] = {};
  float mrow[2][4], lrow[2][4];
#pragma unroll
  for (int m = 0; m < 2; ++m)
#pragma unroll
    for (int r = 0; r < 4; ++r) { mrow[m][r] = -1e30f; lrow[m][r] = 0.f; }

  const int ksr = tid >> 4, ksc = tid & 15;  // K staging: slot row/chunk
  const int vsr = tid >> 3, vsc = tid & 7;   // V staging

  for (int s = 0; s < 32; ++s) {
    const int kv0 = s * 64;
#pragma unroll
    for (int it = 0; it < 4; ++it) {
      int kr = it * 16 + ksr;
      g2lds16(Kb + (size_t)(b * 2048 + kv0 + kr) * 1024 + h * 128 + ((ksc ^ (kr & 7)) << 3),
              K_lds + it * 4096 + (w << 10));
      int vr = it * 32 + vsr;
      g2lds16(Vt + (size_t)(h * 128 + vr) * 8192 + b * 2048 + kv0 + ((vsc ^ (vr & 7)) << 3),
              V_lds + it * 4096 + (w << 10));
    }
    __syncthreads();

    // S = Q K^T  (M=32 q-rows of this wave, N=64 kv)
    f32x4 sacc[2][4];
#pragma unroll
    for (int kk = 0; kk < 4; ++kk) {
      s16x8 kf[4];
#pragma unroll
      for (int n = 0; n < 4; ++n) {
        int kr = n * 16 + q;
        kf[n] = *(const s16x8*)(K_lds + kr * 256 + ((((kk << 2) + g) ^ (kr & 7)) << 4));
      }
#pragma unroll
      for (int m = 0; m < 2; ++m)
#pragma unroll
        for (int n = 0; n < 4; ++n) {
          if (kk == 0) sacc[m][n] = mfma16_z(qf[m][0], kf[n]);
          else         mfma16(sacc[m][n], qf[m][kk], kf[n]);
        }
    }
    asm volatile("s_nop 7\n\ts_nop 7");

    // scale + mask + online softmax (lane owns rows m*16+4g+r, cols n*16+q)
#pragma unroll
    for (int m = 0; m < 2; ++m)
#pragma unroll
      for (int r = 0; r < 4; ++r) {
        u64 pw = pmask[(size_t)(q0 + w * 32 + m * 16 + g * 4 + r) * 32 + s];
        float mx = -1e30f;
#pragma unroll
        for (int n = 0; n < 4; ++n) {
          float sv = sacc[m][n][r] * kScale;
          if ((pw >> (n * 16 + q)) & 1) sv = -1e30f;
          sacc[m][n][r] = sv;
          mx = fmaxf(mx, sv);
        }
        mx = fmaxf(mx, __shfl_xor(mx, 1)); mx = fmaxf(mx, __shfl_xor(mx, 2));
        mx = fmaxf(mx, __shfl_xor(mx, 4)); mx = fmaxf(mx, __shfl_xor(mx, 8));
        float mold = mrow[m][r];
        float mnew = fmaxf(mold, mx);
        float resc = __expf(mold - mnew);
        mrow[m][r] = mnew;
        float rs = 0.f;
#pragma unroll
        for (int n = 0; n < 4; ++n) {
          float pv = __expf(sacc[m][n][r] - mnew);
          sacc[m][n][r] = pv;
          rs += pv;
        }
        rs += __shfl_xor(rs, 1); rs += __shfl_xor(rs, 2);
        rs += __shfl_xor(rs, 4); rs += __shfl_xor(rs, 8);
        lrow[m][r] = lrow[m][r] * resc + rs;
#pragma unroll
        for (int nd = 0; nd < 8; ++nd) oacc[m][nd][r] *= resc;
      }

    // P -> LDS (per-wave region, no barrier needed)
#pragma unroll
    for (int m = 0; m < 2; ++m)
#pragma unroll
      for (int r = 0; r < 4; ++r) {
        int row = w * 32 + m * 16 + g * 4 + r;
#pragma unroll
        for (int n = 0; n < 4; ++n) {
          int colb = (n * 16 + q) << 1;
          int byt = row * 128 + ((((colb >> 4) ^ (row & 7)) << 4) | (colb & 15));
          *(u16*)(P_lds + byt) = f2bf(sacc[m][n][r]);
        }
      }

    // O += P V   (K=64 kv)
#pragma unroll
    for (int kk = 0; kk < 2; ++kk) {
      s16x8 pf[2];
#pragma unroll
      for (int m = 0; m < 2; ++m) {
        int row = w * 32 + m * 16 + q;
        pf[m] = *(const s16x8*)(P_lds + row * 128 + ((((kk << 2) + g) ^ (row & 7)) << 4));
      }
#pragma unroll
      for (int nd = 0; nd < 8; ++nd) {
        int dr = nd * 16 + q;
        s16x8 vf = *(const s16x8*)(V_lds + dr * 128 + ((((kk << 2) + g) ^ (dr & 7)) << 4));
#pragma unroll
        for (int m = 0; m < 2; ++m) mfma16(oacc[m][nd], pf[m], vf);
      }
    }
    __syncthreads();
  }

  asm volatile("s_nop 7\n\ts_nop 7");
  float rl[2][4];
#pragma unroll
  for (int m = 0; m < 2; ++m)
#pragma unroll
    for (int r = 0; r < 4; ++r) rl[m][r] = 1.f / lrow[m][r];
#pragma unroll
  for (int m = 0; m < 2; ++m)
#pragma unroll
    for (int nd = 0; nd < 8; ++nd)
#pragma unroll
      for (int r = 0; r < 4; ++r) {
        size_t trow = (size_t)(b * 2048 + q0 + w * 32 + m * 16 + g * 4 + r);
        Ob[trow * 1024 + h * 128 + nd * 16 + q] = f2bf(oacc[m][nd][r] * rl[m][r]);
      }
}

// ---------------- launcher ----------------
extern "C" void kernel_launch(void* const* d_in, const int* in_sizes, int n_in,
                              void* d_out, int out_size, void* d_ws, size_t ws_size,
                              hipStream_t stream) {
  (void)in_sizes; (void)n_in; (void)out_size; (void)ws_size;
  const float* x    = (const float*)d_in[0];
  const int*   am   = (const int*)d_in[1];
  const float* qkvw = (const float*)d_in[2];
  const float* qkvb = (const float*)d_in[3];
  const float* qw   = (const float*)d_in[4];
  const float* qb   = (const float*)d_in[5];
  const float* kw   = (const float*)d_in[6];
  const float* kb   = (const float*)d_in[7];
  const float* vw   = (const float*)d_in[8];
  const float* vb   = (const float*)d_in[9];
  const float* ow   = (const float*)d_in[10];
  const float* ob   = (const float*)d_in[11];

  char* p = (char*)d_ws;
  auto take = [&](size_t n) { char* r = p; p += (n + 255) & ~(size_t)255; return r; };
  u16* xb    = (u16*)take(8192ull * 1024 * 2);        // also reused as attention output
  u16* qkvwT = (u16*)take(1024ull * 3072 * 2);
  u16* wb4   = (u16*)take(4ull * 1048576 * 2);        // qwb,kwb,vwb,owb
  u16* comb3 = (u16*)take(3ull * 1048576 * 2);        // comb_q, comb_k, comb_v
  float* cb3 = (float*)take(3ull * 1024 * 4);
  u16* QK2   = (u16*)take(2ull * 8192 * 1024 * 2);    // Qbuf, Kbuf
  u16* V2t   = (u16*)take(8192ull * 1024 * 2);
  u64* pm    = (u64*)take(2048ull * 32 * 8);
  u16* Obuf  = xb;                                    // alias: xb dead after projections

  cvt_f32_bf16<<<8192, 256, 0, stream>>>(x, xb, 8192 * 1024);
  cvt4<<<dim3(1024, 4), 256, 0, stream>>>(qw, kw, vw, ow, wb4);
  transpose_f32_bf16<<<dim3(32, 96), 256, 0, stream>>>(qkvw, qkvwT, 3072, 1024);
  cbias3<<<dim3(256, 3), 256, 0, stream>>>(qw, kw, vw, qkvb, qb, kb, vb, cb3);

  // combined weights: comb_z[o][i] = sum_m W_z[o][m] * qkv_w[z*1024+m][i]
  gemm_nt<u16, false><<<dim3(64, 1, 3), 256, 0, stream>>>(
      wb4, 1024, 1048576, qkvwT, 3072, 1024, comb3, 1024, 1048576, nullptr, 0, 8, 1024);
  // Q,K projections (z=2): Q/K[t][o] = x[t]·comb_z[o] + cb_z[o]
  gemm_nt<u16, false><<<dim3(512, 1, 2), 256, 0, stream>>>(
      xb, 1024, 0, comb3, 1024, 1048576, QK2, 1024, 8192ll * 1024, cb3, 1024, 8, 1024);
  // V transposed: V2t[o][t] = comb_v[o]·x[t] + cb_v[o]  (bias per row)
  gemm_nt<u16, true><<<dim3(512, 1, 1), 256, 0, stream>>>(
      comb3 + 2 * 1048576, 1024, 0, xb, 1024, 0, V2t, 8192, 0, cb3 + 2048, 0, 64, 1024);

  pack_mask<<<2048, 256, 0, stream>>>(am, pm);
  attn_fwd<<<dim3(16, 8, 4), 256, 0, stream>>>(QK2, QK2 + 8192ull * 1024, V2t, pm, Obuf);

  // out = O @ out_w^T + out_b  (fp32 output)
  gemm_nt<float, false><<<dim3(512, 1, 1), 256, 0, stream>>>(
      Obuf, 1024, 0, wb4 + 3 * 1048576, 1024, 0, (float*)d_out, 1024, 0, ob, 0, 8, 1024);
}